// Round 2
// baseline (669.958 us; speedup 1.0000x reference)
//
#include <hip/hip_runtime.h>
#include <stdint.h>

// BiDAF co-attention, B=8, L=4096, D=1024, M=2. All inputs/outputs FP32.
// Pipeline: kP (fold weights) -> kA (att per row) -> kB (softmax-L stats)
//        -> kC (output_two accumulation) -> kD (final 4-segment write).

#define BB 8
#define LL 4096
#define DD 1024

// ---- kP: cvec[b][m][d] = w_input[d] + dot_scale[d]*mem[b,m,d]; mdot[bm] = <mem_bm, w_memory>
__global__ __launch_bounds__(256) void kP(const float* __restrict__ mem,
                                          const float* __restrict__ w_in,
                                          const float* __restrict__ w_mem,
                                          const float* __restrict__ ds,
                                          float* __restrict__ cvec,
                                          float* __restrict__ mdot) {
    int bm = blockIdx.x;            // 0..15
    int t  = threadIdx.x;           // 256
    const float* mrow = mem + bm * DD;
    float partial = 0.f;
#pragma unroll
    for (int j = 0; j < 4; ++j) {
        int d = t * 4 + j;
        float m = mrow[d];
        cvec[bm * DD + d] = fmaf(ds[d], m, w_in[d]);
        partial = fmaf(m, w_mem[d], partial);
    }
    __shared__ float red[4];
    for (int off = 32; off; off >>= 1) partial += __shfl_down(partial, off);
    if ((t & 63) == 0) red[t >> 6] = partial;
    __syncthreads();
    if (t == 0) mdot[bm] = red[0] + red[1] + red[2] + red[3];
}

// ---- kA: att[b,l] = (dot(x, c0)+mdot0, dot(x, c1)+mdot1); one wave per row, 16 rows/wave
__global__ __launch_bounds__(256) void kA(const float* __restrict__ input,
                                          const float* __restrict__ cvec,
                                          const float* __restrict__ mdot,
                                          float* __restrict__ att) {
    int blk = blockIdx.x;           // 512 blocks
    int b = blk >> 6, chunk = blk & 63;
    int t = threadIdx.x;
    int wave = t >> 6, lane = t & 63;

    // row-invariant: this lane's slice of the two folded weight vectors
    const float4* c0p = (const float4*)(cvec + (size_t)b * 2 * DD);
    const float4* c1p = (const float4*)(cvec + (size_t)b * 2 * DD + DD);
    float4 rc0[4], rc1[4];
#pragma unroll
    for (int k = 0; k < 4; ++k) { rc0[k] = c0p[lane + 64 * k]; rc1[k] = c1p[lane + 64 * k]; }
    float md0 = mdot[b * 2], md1 = mdot[b * 2 + 1];

    for (int r = 0; r < 16; ++r) {
        int l = chunk * 64 + wave * 16 + r;
        const float4* row = (const float4*)(input + (size_t)(b * LL + l) * DD);
        float a0 = 0.f, a1 = 0.f;
#pragma unroll
        for (int k = 0; k < 4; ++k) {
            float4 x = row[lane + 64 * k];
            a0 = fmaf(x.x, rc0[k].x, a0); a0 = fmaf(x.y, rc0[k].y, a0);
            a0 = fmaf(x.z, rc0[k].z, a0); a0 = fmaf(x.w, rc0[k].w, a0);
            a1 = fmaf(x.x, rc1[k].x, a1); a1 = fmaf(x.y, rc1[k].y, a1);
            a1 = fmaf(x.z, rc1[k].z, a1); a1 = fmaf(x.w, rc1[k].w, a1);
        }
        for (int off = 32; off; off >>= 1) { a0 += __shfl_down(a0, off); a1 += __shfl_down(a1, off); }
        if (lane == 0) {
            ((float2*)att)[(size_t)b * LL + l] = make_float2(a0 + md0, a1 + md1);
        }
    }
}

// ---- kB: per-batch softmax-over-L stats (max, 1/Z) from m_l = max(att0,att1); zero out2u
__global__ __launch_bounds__(256) void kB(const float* __restrict__ att,
                                          float* __restrict__ stats,
                                          float* __restrict__ out2u) {
    int b = blockIdx.x, t = threadIdx.x;
    const float2* a = (const float2*)att + (size_t)b * LL;
    float mv[16];
    float tmax = -1e30f;
#pragma unroll
    for (int j = 0; j < 16; ++j) {
        float2 v = a[j * 256 + t];
        mv[j] = fmaxf(v.x, v.y);
        tmax = fmaxf(tmax, mv[j]);
    }
    __shared__ float red[4];
    for (int off = 32; off; off >>= 1) tmax = fmaxf(tmax, __shfl_down(tmax, off));
    if ((t & 63) == 0) red[t >> 6] = tmax;
    __syncthreads();
    float bmax = fmaxf(fmaxf(red[0], red[1]), fmaxf(red[2], red[3]));
    float s = 0.f;
#pragma unroll
    for (int j = 0; j < 16; ++j) s += __expf(mv[j] - bmax);
    __syncthreads();   // everyone done reading red before it's overwritten
    for (int off = 32; off; off >>= 1) s += __shfl_down(s, off);
    if ((t & 63) == 0) red[t >> 6] = s;
    __syncthreads();
    if (t == 0) { stats[b * 2] = bmax; stats[b * 2 + 1] = 1.f / (red[0] + red[1] + red[2] + red[3]); }
    for (int j = t; j < DD; j += 256) out2u[b * DD + j] = 0.f;
}

// ---- kC: out2u[b,d] += exp(m_l - max_b) * x[b,l,d]  (unnormalized output_two)
__global__ __launch_bounds__(256) void kC(const float* __restrict__ input,
                                          const float* __restrict__ att,
                                          const float* __restrict__ stats,
                                          float* __restrict__ out2u) {
    int blk = blockIdx.x;           // 512 blocks
    int b = blk >> 6, chunk = blk & 63;
    int t = threadIdx.x;
    float bmax = stats[b * 2];
    const float2* a = (const float2*)att + (size_t)b * LL + chunk * 64;
    const float4* inp = (const float4*)(input + (size_t)(b * LL + chunk * 64) * DD);
    float4 acc = make_float4(0.f, 0.f, 0.f, 0.f);
    for (int r = 0; r < 64; ++r) {
        float2 v = a[r];
        float e = __expf(fmaxf(v.x, v.y) - bmax);
        float4 u = inp[(size_t)r * 256 + t];
        acc.x = fmaf(e, u.x, acc.x);
        acc.y = fmaf(e, u.y, acc.y);
        acc.z = fmaf(e, u.z, acc.z);
        acc.w = fmaf(e, u.w, acc.w);
    }
    float* dst = out2u + (size_t)b * DD + 4 * t;
    atomicAdd(dst + 0, acc.x);
    atomicAdd(dst + 1, acc.y);
    atomicAdd(dst + 2, acc.z);
    atomicAdd(dst + 3, acc.w);
}

// ---- kD: final write of [input | o1 | input*o1 | output_two*o1]
__global__ __launch_bounds__(256) void kD(const float* __restrict__ input,
                                          const float* __restrict__ memory,
                                          const float* __restrict__ att,
                                          const float* __restrict__ stats,
                                          const float* __restrict__ out2u,
                                          float* __restrict__ out) {
    int blk = blockIdx.x;           // 2048 blocks: 256 chunks of 16 rows per batch
    int b = blk >> 8, chunk = blk & 255;
    int t = threadIdx.x;
    float invZ = stats[b * 2 + 1];

    float4 m0 = ((const float4*)(memory + (size_t)b * 2 * DD))[t];
    float4 m1 = ((const float4*)(memory + (size_t)b * 2 * DD + DD))[t];
    float4 o2 = ((const float4*)(out2u + (size_t)b * DD))[t];
    o2.x *= invZ; o2.y *= invZ; o2.z *= invZ; o2.w *= invZ;

    const float2* attb = (const float2*)att + (size_t)b * LL + chunk * 16;
    for (int r = 0; r < 16; ++r) {
        int l = chunk * 16 + r;
        float2 v = attb[r];
        float w0 = 1.f / (1.f + __expf(v.y - v.x));   // softmax over M=2
        float w1 = 1.f - w0;
        float4 x = ((const float4*)(input + (size_t)(b * LL + l) * DD))[t];
        float4 o1;
        o1.x = fmaf(w0, m0.x, w1 * m1.x);
        o1.y = fmaf(w0, m0.y, w1 * m1.y);
        o1.z = fmaf(w0, m0.z, w1 * m1.z);
        o1.w = fmaf(w0, m0.w, w1 * m1.w);

        float* orow = out + (size_t)(b * LL + l) * (4 * DD);
        ((float4*)orow)[t] = x;                                                    // seg0
        ((float4*)(orow + DD))[t] = o1;                                            // seg1
        ((float4*)(orow + 2 * DD))[t] = make_float4(x.x * o1.x, x.y * o1.y,
                                                    x.z * o1.z, x.w * o1.w);       // seg2
        ((float4*)(orow + 3 * DD))[t] = make_float4(o2.x * o1.x, o2.y * o1.y,
                                                    o2.z * o1.z, o2.w * o1.w);     // seg3
    }
}

extern "C" void kernel_launch(void* const* d_in, const int* in_sizes, int n_in,
                              void* d_out, int out_size, void* d_ws, size_t ws_size,
                              hipStream_t stream) {
    const float* input  = (const float*)d_in[0];   // [8,4096,1024] fp32
    const float* memory = (const float*)d_in[1];   // [8,2,1024] fp32
    const float* w_in   = (const float*)d_in[2];   // [1024] fp32
    const float* w_mem  = (const float*)d_in[3];   // [1024] fp32
    const float* ds     = (const float*)d_in[4];   // [1024] fp32
    float* out = (float*)d_out;                    // [8,4096,4096] fp32

    // workspace layout (floats): cvec 16384 | mdot 16 | stats 16 | att 65536 | out2u 8192
    float* ws    = (float*)d_ws;
    float* cvec  = ws;
    float* mdot  = ws + 16384;
    float* stats = ws + 16400;
    float* att   = ws + 16416;
    float* out2u = ws + 81952;

    kP<<<16,   256, 0, stream>>>(memory, w_in, w_mem, ds, cvec, mdot);
    kA<<<512,  256, 0, stream>>>(input, cvec, mdot, att);
    kB<<<BB,   256, 0, stream>>>(att, stats, out2u);
    kC<<<512,  256, 0, stream>>>(input, att, stats, out2u);
    kD<<<2048, 256, 0, stream>>>(input, memory, att, stats, out2u, out);
}